// Round 1
// 1077.248 us; speedup vs baseline: 1.5469x; 1.5469x over previous
//
#include <hip/hip_runtime.h>

typedef unsigned int u32;
typedef unsigned short u16;

#define S_LEN 1024
#define NH 32
#define NKV 8
#define DW 64      // dwords per head row (128 bf16 = 64 u32)
#define NEG_BIG (-1e30f)

typedef __bf16 bf16x8 __attribute__((ext_vector_type(8)));
typedef float f32x4 __attribute__((ext_vector_type(4)));

__device__ __forceinline__ u16 f2bf(float f) {
  u32 u = __builtin_bit_cast(u32, f);
  u += 0x7fffu + ((u >> 16) & 1u);   // RNE
  return (u16)(u >> 16);
}
__device__ __forceinline__ float bflo(u32 u) { return __builtin_bit_cast(float, u << 16); }
__device__ __forceinline__ float bfhi(u32 u) { return __builtin_bit_cast(float, u & 0xffff0000u); }

// ---------------------------------------------------------------------------
// C = A @ B^T.  A: (M,K) fp32 or bf16 row-major.  B: (N,K) fp32 row-major.
// C: (M,N) bf16 (BF16OUT) or fp32.  M,N multiples of 128, K multiple of 32.
// 128x128 block tile, 4 waves, each wave 64x64 (4x4 MFMA 16x16x32 bf16 tiles).
// Verified-pattern fragment layouts (m92/m97 ladder):
//   A-frag: A[m=lane&15][k=quad*8+j];  B-frag from B^T: B[n=lane&15][k=quad*8+j]
//   C/D:    row = quad*4+reg, col = lane&15
// ---------------------------------------------------------------------------
template <bool A_BF16, bool BF16OUT>
__launch_bounds__(256)
__global__ void gemm_bt(const void* __restrict__ Av, const float* __restrict__ B,
                        void* __restrict__ Cv, int M, int N, int K) {
  __shared__ u32 As[128 * 16];   // 128 rows x 32 bf16
  __shared__ u32 Bs[128 * 16];
  const int tid = threadIdx.x;
  const int lane = tid & 63, w = tid >> 6;
  const int wr = w >> 1, wc = w & 1;
  const int col = lane & 15, quad = lane >> 4;
  const int m0 = blockIdx.y * 128, n0 = blockIdx.x * 128;

  f32x4 acc[4][4] = {};

  for (int k0 = 0; k0 < K; k0 += 32) {
    // ---- stage A tile (128x32) into As as bf16 ----
    if constexpr (A_BF16) {
      const u16* A = (const u16*)Av;
#pragma unroll
      for (int i = 0; i < 2; ++i) {
        int f = i * 256 + tid;          // 512 uint4 per tile
        int row = f >> 2, c4 = f & 3;
        *(uint4*)&As[row * 16 + c4 * 4] =
            *((const uint4*)(A + (size_t)(m0 + row) * K + k0) + c4);
      }
    } else {
      const float* A = (const float*)Av;
#pragma unroll
      for (int i = 0; i < 4; ++i) {
        int f = i * 256 + tid;          // 1024 float4 per tile
        int row = f >> 3, c4 = f & 7;
        float4 a = *((const float4*)(A + (size_t)(m0 + row) * K + k0) + c4);
        u32 a0 = (u32)f2bf(a.x) | ((u32)f2bf(a.y) << 16);
        u32 a1 = (u32)f2bf(a.z) | ((u32)f2bf(a.w) << 16);
        *(uint2*)&As[row * 16 + c4 * 2] = make_uint2(a0, a1);
      }
    }
    // ---- stage B tile (128x32) fp32 -> bf16 ----
#pragma unroll
    for (int i = 0; i < 4; ++i) {
      int f = i * 256 + tid;
      int row = f >> 3, c4 = f & 7;
      float4 b = *((const float4*)(B + (size_t)(n0 + row) * K + k0) + c4);
      u32 b0 = (u32)f2bf(b.x) | ((u32)f2bf(b.y) << 16);
      u32 b1 = (u32)f2bf(b.z) | ((u32)f2bf(b.w) << 16);
      *(uint2*)&Bs[row * 16 + c4 * 2] = make_uint2(b0, b1);
    }
    __syncthreads();
    bf16x8 af[4], bfr[4];
#pragma unroll
    for (int i = 0; i < 4; ++i) {
      int m = wr * 64 + i * 16 + col;
      af[i] = *reinterpret_cast<const bf16x8*>(&As[m * 16 + quad * 4]);
      int n = wc * 64 + i * 16 + col;
      bfr[i] = *reinterpret_cast<const bf16x8*>(&Bs[n * 16 + quad * 4]);
    }
#pragma unroll
    for (int i = 0; i < 4; ++i)
#pragma unroll
      for (int j = 0; j < 4; ++j)
        acc[i][j] = __builtin_amdgcn_mfma_f32_16x16x32_bf16(af[i], bfr[j], acc[i][j], 0, 0, 0);
    __syncthreads();
  }

#pragma unroll
  for (int i = 0; i < 4; ++i)
#pragma unroll
    for (int j = 0; j < 4; ++j)
#pragma unroll
      for (int r = 0; r < 4; ++r) {
        int row = m0 + wr * 64 + i * 16 + quad * 4 + r;   // C/D: row = quad*4+reg
        int cc  = n0 + wc * 64 + j * 16 + col;            //      col = lane&15
        float v = acc[i][j][r];
        if constexpr (BF16OUT) ((u16*)Cv)[(size_t)row * N + cc] = f2bf(v);
        else                   ((float*)Cv)[(size_t)row * N + cc] = v;
      }
}

// ---------------------------------------------------------------------------
// In-place RoPE on bf16 (B,S,heads,64 pairs). pair p: (x0,x1) packed in u32.
// out_scale folds the attention 1/sqrt(HEAD_DIM) into Q for free.
// ---------------------------------------------------------------------------
__launch_bounds__(256)
__global__ void rope_kernel(u32* __restrict__ buf, int heads, int npairs, float out_scale) {
  int p = blockIdx.x * 256 + threadIdx.x;
  if (p >= npairs) return;
  int d2 = p & 63;
  int s = (p / (64 * heads)) % S_LEN;
  // inv_freq = 10000^(-d2/64) = exp(-d2 * ln(10000)/64)
  float ang = (float)s * expf((float)d2 * -0.14391156831212787f);
  float sn, cs;
  sincosf(ang, &sn, &cs);   // accurate range reduction (ang up to ~1023 rad)
  u32 u = buf[p];
  float x0 = bflo(u), x1 = bfhi(u);
  float y0 = (x0 * cs - x1 * sn) * out_scale;
  float y1 = (x0 * sn + x1 * cs) * out_scale;
  buf[p] = (u32)f2bf(y0) | ((u32)f2bf(y1) << 16);
}

// ---------------------------------------------------------------------------
// MFMA flash attention (causal GQA, online softmax).
// Block = 4 waves = 64 q rows of one (b,h); wave w owns q rows q0..q0+15.
// KV tile = 64 keys. LDS:
//   Ks[64 keys][128 bf16]  row stride 256B, XOR-swizzled (^((key&7)<<4) bytes)
//   Vt[128 d ][ 64 bf16]   row stride 128B, XOR-swizzled (^((d&7)<<4) bytes)
//   Ps[w][16 q][ 64 bf16]  row stride 128B, XOR-swizzled (^((row&7)<<4) bytes)
// QK^T: A-frag = Q (registers), B-frag = K rows (B^T form, K-dim = d).
// PV:   A-frag = P (via Ps),    B-frag = Vt rows (B^T form, K-dim = key).
// C/D layout: row = quad*4+reg, col = lane&15 (same as gemm_bt, verified).
// Softmax state per lane: 4 rows (reg 0..3), uniform across each 16-lane group.
// 1/sqrt(128) is pre-folded into Q by rope_kernel.
// ---------------------------------------------------------------------------
__launch_bounds__(256)
__global__ void attn_kernel(const u32* __restrict__ Qb, const u32* __restrict__ Kb,
                            const u32* __restrict__ Vb, u32* __restrict__ Ob) {
  __shared__ u32 Ks[64 * 64];      // 16 KB
  __shared__ u32 Vt[128 * 32];     // 16 KB
  __shared__ u16 Ps[4][16 * 64];   // 8 KB
  const int tid = threadIdx.x, lane = tid & 63, w = tid >> 6;
  const int col = lane & 15, quad = lane >> 4;
  const int bx = blockIdx.x, h = blockIdx.y, b = blockIdx.z;
  const int kh = h >> 2;           // N_REP = 4
  const int q0 = bx * 64 + w * 16;

  // Q fragments: lane holds Q[q0+col][d = dc*32 + quad*8 + j]
  bf16x8 qf[4];
  {
    const u32* qrow = Qb + ((size_t)((b * S_LEN + q0 + col) * NH + h)) * DW;
#pragma unroll
    for (int dc = 0; dc < 4; ++dc)
      qf[dc] = *reinterpret_cast<const bf16x8*>(qrow + dc * 16 + quad * 4);
  }

  float m_r[4], l_r[4];
  f32x4 oacc[8];
#pragma unroll
  for (int r = 0; r < 4; ++r) { m_r[r] = NEG_BIG; l_r[r] = 0.f; }
#pragma unroll
  for (int dt = 0; dt < 8; ++dt) oacc[dt] = (f32x4){0.f, 0.f, 0.f, 0.f};

  const int ntiles = bx + 1;
  for (int tt = 0; tt < ntiles; ++tt) {
    const int t0 = tt * 64;
    __syncthreads();   // all waves done reading previous tile
    // ---- stage K: 64 rows x 64 dwords, 4 uint4 per thread ----
#pragma unroll
    for (int i = 0; i < 4; ++i) {
      int f = i * 256 + tid;
      int row = f >> 4, c4 = f & 15;
      uint4 kk = *((const uint4*)(Kb + ((size_t)((b * S_LEN + t0 + row) * NKV + kh)) * DW) + c4);
      *(uint4*)&Ks[(row * 64 + c4 * 4) ^ ((row & 7) << 2)] = kk;
    }
    // ---- stage V transposed: thread handles key-pair kp, 8 d's (chunk c8) ----
#pragma unroll
    for (int i = 0; i < 2; ++i) {
      int f = i * 256 + tid;
      int kp = f & 31, c8 = f >> 5;   // kp: key pair 0..31, c8: d-chunk 0..15
      size_t base0 = ((size_t)((b * S_LEN + t0 + 2 * kp) * NKV + kh)) * DW;
      uint4 va = *((const uint4*)(Vb + base0) + c8);
      uint4 vb = *((const uint4*)(Vb + base0 + (size_t)NKV * DW) + c8);
      u32 a[4] = {va.x, va.y, va.z, va.w};
      u32 bbv[4] = {vb.x, vb.y, vb.z, vb.w};
#pragma unroll
      for (int t = 0; t < 4; ++t) {
        int d0 = c8 * 8 + 2 * t, d1 = d0 + 1;
        u32 lo = (a[t] & 0xffffu) | (bbv[t] << 16);
        u32 hi = (a[t] >> 16) | (bbv[t] & 0xffff0000u);
        Vt[(d0 * 32 + kp) ^ ((d0 & 7) << 2)] = lo;
        Vt[(d1 * 32 + kp) ^ ((d1 & 7) << 2)] = hi;
      }
    }
    __syncthreads();

    // ---- QK^T: 16 MFMAs -> sacc[kt] holds S[q=quad*4+r][key=kt*16+col] ----
    f32x4 sacc[4];
#pragma unroll
    for (int kt = 0; kt < 4; ++kt) sacc[kt] = (f32x4){0.f, 0.f, 0.f, 0.f};
#pragma unroll
    for (int dc = 0; dc < 4; ++dc)
#pragma unroll
      for (int kt = 0; kt < 4; ++kt) {
        int key = kt * 16 + col;
        bf16x8 kf = *reinterpret_cast<const bf16x8*>(
            &Ks[(key * 64 + dc * 16 + quad * 4) ^ ((key & 7) << 2)]);
        sacc[kt] = __builtin_amdgcn_mfma_f32_16x16x32_bf16(qf[dc], kf, sacc[kt], 0, 0, 0);
      }

    // ---- causal mask (diagonal tile only; block-uniform branch) ----
    if (tt == ntiles - 1) {
#pragma unroll
      for (int kt = 0; kt < 4; ++kt)
#pragma unroll
        for (int r = 0; r < 4; ++r) {
          int tg = t0 + kt * 16 + col;
          int qg = q0 + quad * 4 + r;
          if (tg > qg) sacc[kt][r] = NEG_BIG;
        }
    }

    // ---- online softmax (4 rows per lane, reduce over 16-lane groups) ----
    float mt[4];
#pragma unroll
    for (int r = 0; r < 4; ++r)
      mt[r] = fmaxf(fmaxf(sacc[0][r], sacc[1][r]), fmaxf(sacc[2][r], sacc[3][r]));
#pragma unroll
    for (int off = 1; off < 16; off <<= 1)
#pragma unroll
      for (int r = 0; r < 4; ++r) mt[r] = fmaxf(mt[r], __shfl_xor(mt[r], off));
    float alpha[4], ps[4];
#pragma unroll
    for (int r = 0; r < 4; ++r) {
      float mn = fmaxf(m_r[r], mt[r]);
      alpha[r] = __expf(m_r[r] - mn);
      m_r[r] = mn;
      ps[r] = 0.f;
    }
    // p = exp(s - m): round to bf16, store to Ps (A-frag source), sum rounded
#pragma unroll
    for (int kt = 0; kt < 4; ++kt)
#pragma unroll
      for (int r = 0; r < 4; ++r) {
        float p = __expf(sacc[kt][r] - m_r[r]);
        u16 pb = f2bf(p);
        int rw = quad * 4 + r;
        Ps[w][(rw * 64 + kt * 16 + col) ^ ((rw & 7) << 3)] = pb;
        ps[r] += bflo((u32)pb);
      }
#pragma unroll
    for (int off = 1; off < 16; off <<= 1)
#pragma unroll
      for (int r = 0; r < 4; ++r) ps[r] += __shfl_xor(ps[r], off);
#pragma unroll
    for (int r = 0; r < 4; ++r) l_r[r] = l_r[r] * alpha[r] + ps[r];
    // rescale O accumulator
#pragma unroll
    for (int dt = 0; dt < 8; ++dt)
#pragma unroll
      for (int r = 0; r < 4; ++r) oacc[dt][r] *= alpha[r];

    // ---- PV: A-frag from Ps (m=col, k=quad*8+j), B-frag from Vt ----
    bf16x8 pa[2];
#pragma unroll
    for (int ks = 0; ks < 2; ++ks)
      pa[ks] = *reinterpret_cast<const bf16x8*>(
          &Ps[w][(col * 64 + ks * 32 + quad * 8) ^ ((col & 7) << 3)]);
#pragma unroll
    for (int dt = 0; dt < 8; ++dt) {
      int d = dt * 16 + col;
#pragma unroll
      for (int ks = 0; ks < 2; ++ks) {
        bf16x8 vf = *reinterpret_cast<const bf16x8*>(
            &Vt[(d * 32 + ks * 16 + quad * 4) ^ ((d & 7) << 2)]);
        oacc[dt] = __builtin_amdgcn_mfma_f32_16x16x32_bf16(pa[ks], vf, oacc[dt], 0, 0, 0);
      }
    }
  }

  // ---- epilogue: O[q][d] = oacc/l ----
  float invl[4];
#pragma unroll
  for (int r = 0; r < 4; ++r) invl[r] = 1.0f / l_r[r];
  u16* O16 = (u16*)Ob;
#pragma unroll
  for (int dt = 0; dt < 8; ++dt)
#pragma unroll
    for (int r = 0; r < 4; ++r) {
      int qg = q0 + quad * 4 + r;
      int d = dt * 16 + col;
      O16[((size_t)((b * S_LEN + qg) * NH + h)) * 128 + d] = f2bf(oacc[dt][r] * invl[r]);
    }
}

// ---------------------------------------------------------------------------
// fp32 inputs & fp32 output (reference dtypes). Internals bf16.
// Plan: Qb bf16 -> d_out (scratch; final fp32 GEMM overwrites all 32 MiB,
//       reading only ws).  ws: [0,4M) Kb | [4M,8M) Vb | [8M,24M) Ob bf16.
// ---------------------------------------------------------------------------
extern "C" void kernel_launch(void* const* d_in, const int* in_sizes, int n_in,
                              void* d_out, int out_size, void* d_ws, size_t ws_size,
                              hipStream_t stream) {
  const float* hs = (const float*)d_in[0];
  const float* Wq = (const float*)d_in[1];
  const float* Wk = (const float*)d_in[2];
  const float* Wv = (const float*)d_in[3];
  const float* Wo = (const float*)d_in[4];

  u16* Qb = (u16*)d_out;
  char* ws = (char*)d_ws;
  u16* Kb = (u16*)ws;
  u16* Vb = (u16*)(ws + (4u << 20));
  u16* Ob = (u16*)(ws + (8u << 20));

  dim3 blk(256);
  // QKV projections (fp32 in, bf16 out)
  gemm_bt<false, true><<<dim3(32, 16), blk, 0, stream>>>(hs, Wq, (void*)Qb, 2048, 4096, 4096);
  gemm_bt<false, true><<<dim3(8, 16), blk, 0, stream>>>(hs, Wk, (void*)Kb, 2048, 1024, 4096);
  gemm_bt<false, true><<<dim3(8, 16), blk, 0, stream>>>(hs, Wv, (void*)Vb, 2048, 1024, 4096);
  // RoPE in-place on Q (with 1/sqrt(128) folded in) and K
  rope_kernel<<<16384, blk, 0, stream>>>((u32*)Qb, NH, 2048 * NH * 64, 0.08838834764831845f);
  rope_kernel<<<4096, blk, 0, stream>>>((u32*)Kb, NKV, 2048 * NKV * 64, 1.0f);
  // causal GQA MFMA flash attention -> Ob bf16 (ws)
  attn_kernel<<<dim3(S_LEN / 64, NH, 2), blk, 0, stream>>>((const u32*)Qb, (const u32*)Kb,
                                                           (const u32*)Vb, (u32*)Ob);
  // output projection: bf16 A (Ob) x fp32 B (Wo) -> fp32 C overwrites d_out
  gemm_bt<true, false><<<dim3(32, 16), blk, 0, stream>>>((const void*)Ob, Wo, d_out,
                                                         2048, 4096, 4096);
}

// Round 2
// 959.738 us; speedup vs baseline: 1.7363x; 1.1224x over previous
//
#include <hip/hip_runtime.h>

typedef unsigned int u32;
typedef unsigned short u16;

#define S_LEN 1024
#define NH 32
#define NKV 8
#define DW 64      // dwords per head row (128 bf16 = 64 u32)
#define NEG_BIG (-1e30f)

typedef __bf16 bf16x8 __attribute__((ext_vector_type(8)));
typedef float f32x4 __attribute__((ext_vector_type(4)));

__device__ __forceinline__ u16 f2bf(float f) {
  u32 u = __builtin_bit_cast(u32, f);
  u += 0x7fffu + ((u >> 16) & 1u);   // RNE
  return (u16)(u >> 16);
}
__device__ __forceinline__ float bflo(u32 u) { return __builtin_bit_cast(float, u << 16); }
__device__ __forceinline__ float bfhi(u32 u) { return __builtin_bit_cast(float, u & 0xffff0000u); }

// ---------------------------------------------------------------------------
// C = A @ B^T.  A: (M,K) fp32 or bf16 row-major.  B: (N,K) fp32 row-major.
// C: (M,N) bf16 (BF16OUT) or fp32.  M,N multiples of 128, K multiple of 32.
// 128x128 block tile, 4 waves, each wave 64x64 (4x4 MFMA 16x16x32 bf16 tiles).
// Verified-pattern fragment layouts (m92/m97 ladder):
//   A-frag: A[m=lane&15][k=quad*8+j];  B-frag from B^T: B[n=lane&15][k=quad*8+j]
//   C/D:    row = quad*4+reg, col = lane&15
// r2: bijective XCD swizzle on linearized wg id (all grids nwg%8==0).
// ---------------------------------------------------------------------------
template <bool A_BF16, bool BF16OUT>
__launch_bounds__(256)
__global__ void gemm_bt(const void* __restrict__ Av, const float* __restrict__ B,
                        void* __restrict__ Cv, int M, int N, int K) {
  __shared__ u32 As[128 * 16];   // 128 rows x 32 bf16
  __shared__ u32 Bs[128 * 16];
  const int tid = threadIdx.x;
  const int lane = tid & 63, w = tid >> 6;
  const int wr = w >> 1, wc = w & 1;
  const int col = lane & 15, quad = lane >> 4;
  // XCD-aware swizzle: consecutive-within-XCD chunks (nwg multiple of 8)
  const int nwg = gridDim.x * gridDim.y;
  const int bid = blockIdx.y * gridDim.x + blockIdx.x;
  const int cpx = nwg >> 3;
  const int sw = (bid & 7) * cpx + (bid >> 3);
  const int m0 = (sw / gridDim.x) * 128, n0 = (sw % gridDim.x) * 128;

  f32x4 acc[4][4] = {};

  for (int k0 = 0; k0 < K; k0 += 32) {
    // ---- stage A tile (128x32) into As as bf16 ----
    if constexpr (A_BF16) {
      const u16* A = (const u16*)Av;
#pragma unroll
      for (int i = 0; i < 2; ++i) {
        int f = i * 256 + tid;          // 512 uint4 per tile
        int row = f >> 2, c4 = f & 3;
        *(uint4*)&As[row * 16 + c4 * 4] =
            *((const uint4*)(A + (size_t)(m0 + row) * K + k0) + c4);
      }
    } else {
      const float* A = (const float*)Av;
#pragma unroll
      for (int i = 0; i < 4; ++i) {
        int f = i * 256 + tid;          // 1024 float4 per tile
        int row = f >> 3, c4 = f & 7;
        float4 a = *((const float4*)(A + (size_t)(m0 + row) * K + k0) + c4);
        u32 a0 = (u32)f2bf(a.x) | ((u32)f2bf(a.y) << 16);
        u32 a1 = (u32)f2bf(a.z) | ((u32)f2bf(a.w) << 16);
        *(uint2*)&As[row * 16 + c4 * 2] = make_uint2(a0, a1);
      }
    }
    // ---- stage B tile (128x32) fp32 -> bf16 ----
#pragma unroll
    for (int i = 0; i < 4; ++i) {
      int f = i * 256 + tid;
      int row = f >> 3, c4 = f & 7;
      float4 b = *((const float4*)(B + (size_t)(n0 + row) * K + k0) + c4);
      u32 b0 = (u32)f2bf(b.x) | ((u32)f2bf(b.y) << 16);
      u32 b1 = (u32)f2bf(b.z) | ((u32)f2bf(b.w) << 16);
      *(uint2*)&Bs[row * 16 + c4 * 2] = make_uint2(b0, b1);
    }
    __syncthreads();
    bf16x8 af[4], bfr[4];
#pragma unroll
    for (int i = 0; i < 4; ++i) {
      int m = wr * 64 + i * 16 + col;
      af[i] = *reinterpret_cast<const bf16x8*>(&As[m * 16 + quad * 4]);
      int n = wc * 64 + i * 16 + col;
      bfr[i] = *reinterpret_cast<const bf16x8*>(&Bs[n * 16 + quad * 4]);
    }
#pragma unroll
    for (int i = 0; i < 4; ++i)
#pragma unroll
      for (int j = 0; j < 4; ++j)
        acc[i][j] = __builtin_amdgcn_mfma_f32_16x16x32_bf16(af[i], bfr[j], acc[i][j], 0, 0, 0);
    __syncthreads();
  }

#pragma unroll
  for (int i = 0; i < 4; ++i)
#pragma unroll
    for (int j = 0; j < 4; ++j)
#pragma unroll
      for (int r = 0; r < 4; ++r) {
        int row = m0 + wr * 64 + i * 16 + quad * 4 + r;   // C/D: row = quad*4+reg
        int cc  = n0 + wc * 64 + j * 16 + col;            //      col = lane&15
        float v = acc[i][j][r];
        if constexpr (BF16OUT) ((u16*)Cv)[(size_t)row * N + cc] = f2bf(v);
        else                   ((float*)Cv)[(size_t)row * N + cc] = v;
      }
}

// ---------------------------------------------------------------------------
// In-place RoPE on bf16 (B,S,heads,64 pairs). pair p: (x0,x1) packed in u32.
// out_scale folds the attention 1/sqrt(HEAD_DIM) into Q for free.
// ---------------------------------------------------------------------------
__launch_bounds__(256)
__global__ void rope_kernel(u32* __restrict__ buf, int heads, int npairs, float out_scale) {
  int p = blockIdx.x * 256 + threadIdx.x;
  if (p >= npairs) return;
  int d2 = p & 63;
  int s = (p / (64 * heads)) % S_LEN;
  // inv_freq = 10000^(-d2/64) = exp(-d2 * ln(10000)/64)
  float ang = (float)s * expf((float)d2 * -0.14391156831212787f);
  float sn, cs;
  sincosf(ang, &sn, &cs);   // accurate range reduction (ang up to ~1023 rad)
  u32 u = buf[p];
  float x0 = bflo(u), x1 = bfhi(u);
  float y0 = (x0 * cs - x1 * sn) * out_scale;
  float y1 = (x0 * sn + x1 * cs) * out_scale;
  buf[p] = (u32)f2bf(y0) | ((u32)f2bf(y1) << 16);
}

// ---------------------------------------------------------------------------
// MFMA flash attention (causal GQA, online softmax).
// Block = 4 waves = 64 q rows of one (b,h); wave w owns q rows q0..q0+15.
// KV tile = 64 keys. LDS:
//   Ks[64 keys][128 bf16]  row stride 256B, XOR-swizzled (^((key&7)<<4) bytes)
//   Vt[128 d ][ 64 bf16]   row stride 128B, XOR-swizzled (^((d&7)<<4) bytes)
//   Ps[w][16 q][ 64 bf16]  row stride 128B, XOR-swizzled (^((row&7)<<4) bytes)
// QK^T: A-frag = Q (registers), B-frag = K rows (B^T form, K-dim = d).
// PV:   A-frag = P (via Ps),    B-frag = Vt rows (B^T form, K-dim = key).
// C/D layout: row = quad*4+reg, col = lane&15 (same as gemm_bt, verified).
// 1/sqrt(128) is pre-folded into Q by rope_kernel.
// r2 changes (latency theory — all pipes <11% busy in r1 counters):
//  * register-prefetch pipeline, distance 1: global loads for tile t+1 issue
//    right after the barrier publishing tile t, fly under compute(t). The
//    vmcnt(0) drain inside the next __syncthreads then waits on loads that
//    already landed. Plain __syncthreads everywhere => compiler-managed
//    correctness (no raw-barrier hazards).
//  * bx reversed: heavy (16-tile) blocks dispatch first, 1-tile blocks fill
//    the drain tail.
// ---------------------------------------------------------------------------
__launch_bounds__(256)
__global__ void attn_kernel(const u32* __restrict__ Qb, const u32* __restrict__ Kb,
                            const u32* __restrict__ Vb, u32* __restrict__ Ob) {
  __shared__ u32 Ks[64 * 64];      // 16 KB
  __shared__ u32 Vt[128 * 32];     // 16 KB
  __shared__ u16 Ps[4][16 * 64];   // 8 KB
  const int tid = threadIdx.x, lane = tid & 63, w = tid >> 6;
  const int col = lane & 15, quad = lane >> 4;
  const int h = blockIdx.y, b = blockIdx.z;
  const int bx = gridDim.x - 1 - blockIdx.x;   // heavy blocks first
  const int kh = h >> 2;           // N_REP = 4
  const int q0 = bx * 64 + w * 16;

  // Q fragments: lane holds Q[q0+col][d = dc*32 + quad*8 + j]
  bf16x8 qf[4];
  {
    const u32* qrow = Qb + ((size_t)((b * S_LEN + q0 + col) * NH + h)) * DW;
#pragma unroll
    for (int dc = 0; dc < 4; ++dc)
      qf[dc] = *reinterpret_cast<const bf16x8*>(qrow + dc * 16 + quad * 4);
  }

  float m_r[4], l_r[4];
  f32x4 oacc[8];
#pragma unroll
  for (int r = 0; r < 4; ++r) { m_r[r] = NEG_BIG; l_r[r] = 0.f; }
#pragma unroll
  for (int dt = 0; dt < 8; ++dt) oacc[dt] = (f32x4){0.f, 0.f, 0.f, 0.f};

  // ---- prefetch registers (tile t+1 in flight during compute of tile t) ----
  uint4 kpf[4], vpa[2], vpb[2];
  auto prefetch = [&](int t0) {
#pragma unroll
    for (int i = 0; i < 4; ++i) {
      int f = i * 256 + tid;
      int row = f >> 4, c4 = f & 15;
      kpf[i] = *((const uint4*)(Kb + ((size_t)((b * S_LEN + t0 + row) * NKV + kh)) * DW) + c4);
    }
#pragma unroll
    for (int i = 0; i < 2; ++i) {
      int f = i * 256 + tid;
      int kp = f & 31, c8 = f >> 5;   // kp: key pair 0..31, c8: d-chunk 0..15
      size_t base0 = ((size_t)((b * S_LEN + t0 + 2 * kp) * NKV + kh)) * DW;
      vpa[i] = *((const uint4*)(Vb + base0) + c8);
      vpb[i] = *((const uint4*)(Vb + base0 + (size_t)NKV * DW) + c8);
    }
  };

  const int ntiles = bx + 1;
  prefetch(0);

  for (int tt = 0; tt < ntiles; ++tt) {
    const int t0 = tt * 64;
    __syncthreads();   // readers of tile t-1 done; drains vmcnt for prefetched t
    // ---- stage K from prefetch regs: 64 rows x 64 dwords ----
#pragma unroll
    for (int i = 0; i < 4; ++i) {
      int f = i * 256 + tid;
      int row = f >> 4, c4 = f & 15;
      *(uint4*)&Ks[(row * 64 + c4 * 4) ^ ((row & 7) << 2)] = kpf[i];
    }
    // ---- stage V transposed from prefetch regs ----
#pragma unroll
    for (int i = 0; i < 2; ++i) {
      int f = i * 256 + tid;
      int kp = f & 31, c8 = f >> 5;
      u32 a[4] = {vpa[i].x, vpa[i].y, vpa[i].z, vpa[i].w};
      u32 bbv[4] = {vpb[i].x, vpb[i].y, vpb[i].z, vpb[i].w};
#pragma unroll
      for (int t = 0; t < 4; ++t) {
        int d0 = c8 * 8 + 2 * t, d1 = d0 + 1;
        u32 lo = (a[t] & 0xffffu) | (bbv[t] << 16);
        u32 hi = (a[t] >> 16) | (bbv[t] & 0xffff0000u);
        Vt[(d0 * 32 + kp) ^ ((d0 & 7) << 2)] = lo;
        Vt[(d1 * 32 + kp) ^ ((d1 & 7) << 2)] = hi;
      }
    }
    __syncthreads();   // LDS tile t published (drains lgkmcnt; no vm outstanding)

    // ---- issue next-tile loads: fly under the whole compute phase ----
    if (tt + 1 < ntiles) prefetch(t0 + 64);

    // ---- QK^T: 16 MFMAs -> sacc[kt] holds S[q=quad*4+r][key=kt*16+col] ----
    f32x4 sacc[4];
#pragma unroll
    for (int kt = 0; kt < 4; ++kt) sacc[kt] = (f32x4){0.f, 0.f, 0.f, 0.f};
#pragma unroll
    for (int dc = 0; dc < 4; ++dc)
#pragma unroll
      for (int kt = 0; kt < 4; ++kt) {
        int key = kt * 16 + col;
        bf16x8 kf = *reinterpret_cast<const bf16x8*>(
            &Ks[(key * 64 + dc * 16 + quad * 4) ^ ((key & 7) << 2)]);
        sacc[kt] = __builtin_amdgcn_mfma_f32_16x16x32_bf16(qf[dc], kf, sacc[kt], 0, 0, 0);
      }

    // ---- causal mask (diagonal tile only; block-uniform branch) ----
    if (tt == ntiles - 1) {
#pragma unroll
      for (int kt = 0; kt < 4; ++kt)
#pragma unroll
        for (int r = 0; r < 4; ++r) {
          int tg = t0 + kt * 16 + col;
          int qg = q0 + quad * 4 + r;
          if (tg > qg) sacc[kt][r] = NEG_BIG;
        }
    }

    // ---- online softmax (4 rows per lane, reduce over 16-lane groups) ----
    float mt[4];
#pragma unroll
    for (int r = 0; r < 4; ++r)
      mt[r] = fmaxf(fmaxf(sacc[0][r], sacc[1][r]), fmaxf(sacc[2][r], sacc[3][r]));
#pragma unroll
    for (int off = 1; off < 16; off <<= 1)
#pragma unroll
      for (int r = 0; r < 4; ++r) mt[r] = fmaxf(mt[r], __shfl_xor(mt[r], off));
    float alpha[4], ps[4];
#pragma unroll
    for (int r = 0; r < 4; ++r) {
      float mn = fmaxf(m_r[r], mt[r]);
      alpha[r] = __expf(m_r[r] - mn);
      m_r[r] = mn;
      ps[r] = 0.f;
    }
    // p = exp(s - m): round to bf16, store to Ps (A-frag source), sum rounded
#pragma unroll
    for (int kt = 0; kt < 4; ++kt)
#pragma unroll
      for (int r = 0; r < 4; ++r) {
        float p = __expf(sacc[kt][r] - m_r[r]);
        u16 pb = f2bf(p);
        int rw = quad * 4 + r;
        Ps[w][(rw * 64 + kt * 16 + col) ^ ((rw & 7) << 3)] = pb;
        ps[r] += bflo((u32)pb);
      }
#pragma unroll
    for (int off = 1; off < 16; off <<= 1)
#pragma unroll
      for (int r = 0; r < 4; ++r) ps[r] += __shfl_xor(ps[r], off);
#pragma unroll
    for (int r = 0; r < 4; ++r) l_r[r] = l_r[r] * alpha[r] + ps[r];
    // rescale O accumulator
#pragma unroll
    for (int dt = 0; dt < 8; ++dt)
#pragma unroll
      for (int r = 0; r < 4; ++r) oacc[dt][r] *= alpha[r];

    // ---- PV: A-frag from Ps (m=col, k=quad*8+j), B-frag from Vt ----
    bf16x8 pa[2];
#pragma unroll
    for (int ks = 0; ks < 2; ++ks)
      pa[ks] = *reinterpret_cast<const bf16x8*>(
          &Ps[w][(col * 64 + ks * 32 + quad * 8) ^ ((col & 7) << 3)]);
#pragma unroll
    for (int dt = 0; dt < 8; ++dt) {
      int d = dt * 16 + col;
#pragma unroll
      for (int ks = 0; ks < 2; ++ks) {
        bf16x8 vf = *reinterpret_cast<const bf16x8*>(
            &Vt[(d * 32 + ks * 16 + quad * 4) ^ ((d & 7) << 2)]);
        oacc[dt] = __builtin_amdgcn_mfma_f32_16x16x32_bf16(pa[ks], vf, oacc[dt], 0, 0, 0);
      }
    }
  }

  // ---- epilogue: O[q][d] = oacc/l ----
  float invl[4];
#pragma unroll
  for (int r = 0; r < 4; ++r) invl[r] = 1.0f / l_r[r];
  u16* O16 = (u16*)Ob;
#pragma unroll
  for (int dt = 0; dt < 8; ++dt)
#pragma unroll
    for (int r = 0; r < 4; ++r) {
      int qg = q0 + quad * 4 + r;
      int d = dt * 16 + col;
      O16[((size_t)((b * S_LEN + qg) * NH + h)) * 128 + d] = f2bf(oacc[dt][r] * invl[r]);
    }
}

// ---------------------------------------------------------------------------
// fp32 inputs & fp32 output (reference dtypes). Internals bf16.
// Plan: Qb bf16 -> d_out (scratch; final fp32 GEMM overwrites all 32 MiB,
//       reading only ws).  ws: [0,4M) Kb | [4M,8M) Vb | [8M,24M) Ob bf16.
// ---------------------------------------------------------------------------
extern "C" void kernel_launch(void* const* d_in, const int* in_sizes, int n_in,
                              void* d_out, int out_size, void* d_ws, size_t ws_size,
                              hipStream_t stream) {
  const float* hs = (const float*)d_in[0];
  const float* Wq = (const float*)d_in[1];
  const float* Wk = (const float*)d_in[2];
  const float* Wv = (const float*)d_in[3];
  const float* Wo = (const float*)d_in[4];

  u16* Qb = (u16*)d_out;
  char* ws = (char*)d_ws;
  u16* Kb = (u16*)ws;
  u16* Vb = (u16*)(ws + (4u << 20));
  u16* Ob = (u16*)(ws + (8u << 20));

  dim3 blk(256);
  // QKV projections (fp32 in, bf16 out)
  gemm_bt<false, true><<<dim3(32, 16), blk, 0, stream>>>(hs, Wq, (void*)Qb, 2048, 4096, 4096);
  gemm_bt<false, true><<<dim3(8, 16), blk, 0, stream>>>(hs, Wk, (void*)Kb, 2048, 1024, 4096);
  gemm_bt<false, true><<<dim3(8, 16), blk, 0, stream>>>(hs, Wv, (void*)Vb, 2048, 1024, 4096);
  // RoPE in-place on Q (with 1/sqrt(128) folded in) and K
  rope_kernel<<<16384, blk, 0, stream>>>((u32*)Qb, NH, 2048 * NH * 64, 0.08838834764831845f);
  rope_kernel<<<4096, blk, 0, stream>>>((u32*)Kb, NKV, 2048 * NKV * 64, 1.0f);
  // causal GQA MFMA flash attention -> Ob bf16 (ws)
  attn_kernel<<<dim3(S_LEN / 64, NH, 2), blk, 0, stream>>>((const u32*)Qb, (const u32*)Kb,
                                                           (const u32*)Vb, (u32*)Ob);
  // output projection: bf16 A (Ob) x fp32 B (Wo) -> fp32 C overwrites d_out
  gemm_bt<true, false><<<dim3(32, 16), blk, 0, stream>>>((const void*)Ob, Wo, d_out,
                                                         2048, 4096, 4096);
}

// Round 3
// 632.599 us; speedup vs baseline: 2.6341x; 1.5171x over previous
//
#include <hip/hip_runtime.h>

typedef unsigned int u32;
typedef unsigned short u16;

#define S_LEN 1024
#define NH 32
#define NKV 8
#define DW 64      // dwords per head row (128 bf16 = 64 u32)
#define NEG_BIG (-1e30f)

typedef __bf16 bf16x8 __attribute__((ext_vector_type(8)));
typedef float f32x4 __attribute__((ext_vector_type(4)));

__device__ __forceinline__ u16 f2bf(float f) {
  u32 u = __builtin_bit_cast(u32, f);
  u += 0x7fffu + ((u >> 16) & 1u);   // RNE
  return (u16)(u >> 16);
}
__device__ __forceinline__ float bflo(u32 u) { return __builtin_bit_cast(float, u << 16); }
__device__ __forceinline__ float bfhi(u32 u) { return __builtin_bit_cast(float, u & 0xffff0000u); }

// global -> LDS direct DMA, 16B per lane. LDS dest is wave-uniform base;
// HW writes lane l at base + l*16 (m97-verified pattern).
__device__ __forceinline__ void gl_lds16(const u16* g, u32* l) {
  __builtin_amdgcn_global_load_lds(
      (__attribute__((address_space(1))) void*)const_cast<u16*>(g),
      (__attribute__((address_space(3))) void*)l, 16, 0, 0);
}

// ---------------------------------------------------------------------------
// fp32 -> bf16 streaming conversion, 8 elems/thread (32B read, 16B write).
// Grids are launched exact (all sizes divisible by 2048 elems).
// ---------------------------------------------------------------------------
__launch_bounds__(256)
__global__ void cvt_bf16(const float4* __restrict__ in, uint4* __restrict__ out, int n8) {
  int i = blockIdx.x * 256 + threadIdx.x;
  if (i >= n8) return;
  float4 a = in[2 * i], b = in[2 * i + 1];
  uint4 o;
  o.x = (u32)f2bf(a.x) | ((u32)f2bf(a.y) << 16);
  o.y = (u32)f2bf(a.z) | ((u32)f2bf(a.w) << 16);
  o.z = (u32)f2bf(b.x) | ((u32)f2bf(b.y) << 16);
  o.w = (u32)f2bf(b.z) | ((u32)f2bf(b.w) << 16);
  out[i] = o;
}

// ---------------------------------------------------------------------------
// C = A @ B^T, all-bf16 inputs.  A: (M,K) bf16.  B: (N,K) bf16 row-major.
// C: bf16 (BF16OUT) or fp32.  128x128 tile, 4 waves, 4x4 MFMA 16x16x32 tiles.
// Staging via global_load_lds (16B/lane, lane-linear LDS == As[row][32bf16]).
// Fragment layouts (m92/m97-verified):
//   A-frag: A[m=lane&15][k=quad*8+j];  B-frag from B^T: B[n=lane&15][k=quad*8+j]
//   C/D:    row = quad*4+reg, col = lane&15
// SPLIT: N=2048 KV-fused; n<1024 -> Cv (Kb), else Cv2 (Vb), both stride 1024.
// r3: this kernel replaces the fp32-staging gemm_bt (VALU-bound: MfmaUtil 13%,
// VALUBusy 41% in r2 counters).
// ---------------------------------------------------------------------------
template <bool BF16OUT, bool SPLIT>
__launch_bounds__(256)
__global__ void gemm16(const u16* __restrict__ A, const u16* __restrict__ B,
                       void* __restrict__ Cv, void* __restrict__ Cv2,
                       int M, int N, int K) {
  __shared__ u32 As[128 * 16];   // 128 rows x 32 bf16 (8 KB)
  __shared__ u32 Bs[128 * 16];
  const int tid = threadIdx.x;
  const int lane = tid & 63, w = tid >> 6;
  const int wr = w >> 1, wc = w & 1;
  const int col = lane & 15, quad = lane >> 4;
  // bijective XCD swizzle (all grids have nwg % 8 == 0)
  const int nwg = gridDim.x * gridDim.y;
  const int bid = blockIdx.y * gridDim.x + blockIdx.x;
  const int cpx = nwg >> 3;
  const int sw = (bid & 7) * cpx + (bid >> 3);
  const int m0 = (sw / gridDim.x) * 128, n0 = (sw % gridDim.x) * 128;

  // per-lane global srcs: f = i*256 + tid -> row = i*64 + (tid>>2), c4 = tid&3
  const u16* ap0 = A + (size_t)(m0 + (tid >> 2)) * K + (tid & 3) * 8;
  const u16* ap1 = ap0 + (size_t)64 * K;
  const u16* bp0 = B + (size_t)(n0 + (tid >> 2)) * K + (tid & 3) * 8;
  const u16* bp1 = bp0 + (size_t)64 * K;
  u32* asd0 = &As[w * 256];        // wave-uniform LDS bases (i*1024 + w*256)
  u32* asd1 = &As[1024 + w * 256];
  u32* bsd0 = &Bs[w * 256];
  u32* bsd1 = &Bs[1024 + w * 256];

  f32x4 acc[4][4] = {};

  for (int k0 = 0; k0 < K; k0 += 32) {
    gl_lds16(ap0 + k0, asd0);
    gl_lds16(ap1 + k0, asd1);
    gl_lds16(bp0 + k0, bsd0);
    gl_lds16(bp1 + k0, bsd1);
    __syncthreads();   // drains vmcnt(0): LDS tiles ready

    bf16x8 af[4], bfr[4];
#pragma unroll
    for (int i = 0; i < 4; ++i) {
      int m = wr * 64 + i * 16 + col;
      af[i] = *reinterpret_cast<const bf16x8*>(&As[m * 16 + quad * 4]);
      int n = wc * 64 + i * 16 + col;
      bfr[i] = *reinterpret_cast<const bf16x8*>(&Bs[n * 16 + quad * 4]);
    }
#pragma unroll
    for (int i = 0; i < 4; ++i)
#pragma unroll
      for (int j = 0; j < 4; ++j)
        acc[i][j] = __builtin_amdgcn_mfma_f32_16x16x32_bf16(af[i], bfr[j], acc[i][j], 0, 0, 0);
    __syncthreads();   // readers done before next DMA overwrites
  }

#pragma unroll
  for (int i = 0; i < 4; ++i)
#pragma unroll
    for (int j = 0; j < 4; ++j)
#pragma unroll
      for (int r = 0; r < 4; ++r) {
        int row = m0 + wr * 64 + i * 16 + quad * 4 + r;   // C/D: row = quad*4+reg
        int cc  = n0 + wc * 64 + j * 16 + col;            //      col = lane&15
        float v = acc[i][j][r];
        if constexpr (SPLIT) {
          u16* dst = (cc >> 10) ? (u16*)Cv2 : (u16*)Cv;
          dst[(size_t)row * 1024 + (cc & 1023)] = f2bf(v);
        } else if constexpr (BF16OUT) {
          ((u16*)Cv)[(size_t)row * N + cc] = f2bf(v);
        } else {
          ((float*)Cv)[(size_t)row * N + cc] = v;
        }
      }
}

// ---------------------------------------------------------------------------
// In-place RoPE on bf16 (B,S,heads,64 pairs). pair p: (x0,x1) packed in u32.
// out_scale folds the attention 1/sqrt(HEAD_DIM) into Q for free.
// ---------------------------------------------------------------------------
__launch_bounds__(256)
__global__ void rope_kernel(u32* __restrict__ buf, int heads, int npairs, float out_scale) {
  int p = blockIdx.x * 256 + threadIdx.x;
  if (p >= npairs) return;
  int d2 = p & 63;
  int s = (p / (64 * heads)) % S_LEN;
  float ang = (float)s * expf((float)d2 * -0.14391156831212787f);
  float sn, cs;
  sincosf(ang, &sn, &cs);
  u32 u = buf[p];
  float x0 = bflo(u), x1 = bfhi(u);
  float y0 = (x0 * cs - x1 * sn) * out_scale;
  float y1 = (x0 * sn + x1 * cs) * out_scale;
  buf[p] = (u32)f2bf(y0) | ((u32)f2bf(y1) << 16);
}

// ---------------------------------------------------------------------------
// MFMA flash attention (causal GQA, online softmax). Unchanged from r2
// (register-prefetch pipeline + reversed bx; verified passing).
// ---------------------------------------------------------------------------
__launch_bounds__(256)
__global__ void attn_kernel(const u32* __restrict__ Qb, const u32* __restrict__ Kb,
                            const u32* __restrict__ Vb, u32* __restrict__ Ob) {
  __shared__ u32 Ks[64 * 64];      // 16 KB
  __shared__ u32 Vt[128 * 32];     // 16 KB
  __shared__ u16 Ps[4][16 * 64];   // 8 KB
  const int tid = threadIdx.x, lane = tid & 63, w = tid >> 6;
  const int col = lane & 15, quad = lane >> 4;
  const int h = blockIdx.y, b = blockIdx.z;
  const int bx = gridDim.x - 1 - blockIdx.x;   // heavy blocks first
  const int kh = h >> 2;           // N_REP = 4
  const int q0 = bx * 64 + w * 16;

  bf16x8 qf[4];
  {
    const u32* qrow = Qb + ((size_t)((b * S_LEN + q0 + col) * NH + h)) * DW;
#pragma unroll
    for (int dc = 0; dc < 4; ++dc)
      qf[dc] = *reinterpret_cast<const bf16x8*>(qrow + dc * 16 + quad * 4);
  }

  float m_r[4], l_r[4];
  f32x4 oacc[8];
#pragma unroll
  for (int r = 0; r < 4; ++r) { m_r[r] = NEG_BIG; l_r[r] = 0.f; }
#pragma unroll
  for (int dt = 0; dt < 8; ++dt) oacc[dt] = (f32x4){0.f, 0.f, 0.f, 0.f};

  uint4 kpf[4], vpa[2], vpb[2];
  auto prefetch = [&](int t0) {
#pragma unroll
    for (int i = 0; i < 4; ++i) {
      int f = i * 256 + tid;
      int row = f >> 4, c4 = f & 15;
      kpf[i] = *((const uint4*)(Kb + ((size_t)((b * S_LEN + t0 + row) * NKV + kh)) * DW) + c4);
    }
#pragma unroll
    for (int i = 0; i < 2; ++i) {
      int f = i * 256 + tid;
      int kp = f & 31, c8 = f >> 5;
      size_t base0 = ((size_t)((b * S_LEN + t0 + 2 * kp) * NKV + kh)) * DW;
      vpa[i] = *((const uint4*)(Vb + base0) + c8);
      vpb[i] = *((const uint4*)(Vb + base0 + (size_t)NKV * DW) + c8);
    }
  };

  const int ntiles = bx + 1;
  prefetch(0);

  for (int tt = 0; tt < ntiles; ++tt) {
    const int t0 = tt * 64;
    __syncthreads();
#pragma unroll
    for (int i = 0; i < 4; ++i) {
      int f = i * 256 + tid;
      int row = f >> 4, c4 = f & 15;
      *(uint4*)&Ks[(row * 64 + c4 * 4) ^ ((row & 7) << 2)] = kpf[i];
    }
#pragma unroll
    for (int i = 0; i < 2; ++i) {
      int f = i * 256 + tid;
      int kp = f & 31, c8 = f >> 5;
      u32 a[4] = {vpa[i].x, vpa[i].y, vpa[i].z, vpa[i].w};
      u32 bbv[4] = {vpb[i].x, vpb[i].y, vpb[i].z, vpb[i].w};
#pragma unroll
      for (int t = 0; t < 4; ++t) {
        int d0 = c8 * 8 + 2 * t, d1 = d0 + 1;
        u32 lo = (a[t] & 0xffffu) | (bbv[t] << 16);
        u32 hi = (a[t] >> 16) | (bbv[t] & 0xffff0000u);
        Vt[(d0 * 32 + kp) ^ ((d0 & 7) << 2)] = lo;
        Vt[(d1 * 32 + kp) ^ ((d1 & 7) << 2)] = hi;
      }
    }
    __syncthreads();

    if (tt + 1 < ntiles) prefetch(t0 + 64);

    f32x4 sacc[4];
#pragma unroll
    for (int kt = 0; kt < 4; ++kt) sacc[kt] = (f32x4){0.f, 0.f, 0.f, 0.f};
#pragma unroll
    for (int dc = 0; dc < 4; ++dc)
#pragma unroll
      for (int kt = 0; kt < 4; ++kt) {
        int key = kt * 16 + col;
        bf16x8 kf = *reinterpret_cast<const bf16x8*>(
            &Ks[(key * 64 + dc * 16 + quad * 4) ^ ((key & 7) << 2)]);
        sacc[kt] = __builtin_amdgcn_mfma_f32_16x16x32_bf16(qf[dc], kf, sacc[kt], 0, 0, 0);
      }

    if (tt == ntiles - 1) {
#pragma unroll
      for (int kt = 0; kt < 4; ++kt)
#pragma unroll
        for (int r = 0; r < 4; ++r) {
          int tg = t0 + kt * 16 + col;
          int qg = q0 + quad * 4 + r;
          if (tg > qg) sacc[kt][r] = NEG_BIG;
        }
    }

    float mt[4];
#pragma unroll
    for (int r = 0; r < 4; ++r)
      mt[r] = fmaxf(fmaxf(sacc[0][r], sacc[1][r]), fmaxf(sacc[2][r], sacc[3][r]));
#pragma unroll
    for (int off = 1; off < 16; off <<= 1)
#pragma unroll
      for (int r = 0; r < 4; ++r) mt[r] = fmaxf(mt[r], __shfl_xor(mt[r], off));
    float alpha[4], ps[4];
#pragma unroll
    for (int r = 0; r < 4; ++r) {
      float mn = fmaxf(m_r[r], mt[r]);
      alpha[r] = __expf(m_r[r] - mn);
      m_r[r] = mn;
      ps[r] = 0.f;
    }
#pragma unroll
    for (int kt = 0; kt < 4; ++kt)
#pragma unroll
      for (int r = 0; r < 4; ++r) {
        float p = __expf(sacc[kt][r] - m_r[r]);
        u16 pb = f2bf(p);
        int rw = quad * 4 + r;
        Ps[w][(rw * 64 + kt * 16 + col) ^ ((rw & 7) << 3)] = pb;
        ps[r] += bflo((u32)pb);
      }
#pragma unroll
    for (int off = 1; off < 16; off <<= 1)
#pragma unroll
      for (int r = 0; r < 4; ++r) ps[r] += __shfl_xor(ps[r], off);
#pragma unroll
    for (int r = 0; r < 4; ++r) l_r[r] = l_r[r] * alpha[r] + ps[r];
#pragma unroll
    for (int dt = 0; dt < 8; ++dt)
#pragma unroll
      for (int r = 0; r < 4; ++r) oacc[dt][r] *= alpha[r];

    bf16x8 pa[2];
#pragma unroll
    for (int ks = 0; ks < 2; ++ks)
      pa[ks] = *reinterpret_cast<const bf16x8*>(
          &Ps[w][(col * 64 + ks * 32 + quad * 8) ^ ((col & 7) << 3)]);
#pragma unroll
    for (int dt = 0; dt < 8; ++dt) {
      int d = dt * 16 + col;
#pragma unroll
      for (int ks = 0; ks < 2; ++ks) {
        bf16x8 vf = *reinterpret_cast<const bf16x8*>(
            &Vt[(d * 32 + ks * 16 + quad * 4) ^ ((d & 7) << 2)]);
        oacc[dt] = __builtin_amdgcn_mfma_f32_16x16x32_bf16(pa[ks], vf, oacc[dt], 0, 0, 0);
      }
    }
  }

  float invl[4];
#pragma unroll
  for (int r = 0; r < 4; ++r) invl[r] = 1.0f / l_r[r];
  u16* O16 = (u16*)Ob;
#pragma unroll
  for (int dt = 0; dt < 8; ++dt)
#pragma unroll
    for (int r = 0; r < 4; ++r) {
      int qg = q0 + quad * 4 + r;
      int d = dt * 16 + col;
      O16[((size_t)((b * S_LEN + qg) * NH + h)) * 128 + d] = f2bf(oacc[dt][r] * invl[r]);
    }
}

// ---------------------------------------------------------------------------
// fp32 in / fp32 out. Internals bf16 via one-shot conversion kernels.
// d_out: [0,16M) Qb bf16 | [16M,32M) hs16 bf16 (dead before final GEMM write).
// ws:    [0,4M) Kb | [4M,8M) Vb | [8M,24M) Ob | [24M,56M) W-scratch
//        (Wq16 -> Wkv16 -> Wo16, serialized reuse; stream-ordered).
// ---------------------------------------------------------------------------
extern "C" void kernel_launch(void* const* d_in, const int* in_sizes, int n_in,
                              void* d_out, int out_size, void* d_ws, size_t ws_size,
                              hipStream_t stream) {
  const float* hs = (const float*)d_in[0];
  const float* Wq = (const float*)d_in[1];
  const float* Wk = (const float*)d_in[2];
  const float* Wv = (const float*)d_in[3];
  const float* Wo = (const float*)d_in[4];

  u16* Qb   = (u16*)d_out;
  u16* hs16 = (u16*)((char*)d_out + (16u << 20));
  char* ws = (char*)d_ws;
  u16* Kb  = (u16*)ws;
  u16* Vb  = (u16*)(ws + (4u << 20));
  u16* Ob  = (u16*)(ws + (8u << 20));
  u16* Wsc = (u16*)(ws + (24u << 20));   // 32 MB serialized scratch

  dim3 blk(256);
  // hs -> bf16 (2048x4096), Wq -> bf16 (4096x4096)
  cvt_bf16<<<4096, blk, 0, stream>>>((const float4*)hs, (uint4*)hs16, 1048576);
  cvt_bf16<<<8192, blk, 0, stream>>>((const float4*)Wq, (uint4*)Wsc, 2097152);
  // Q projection
  gemm16<true, false><<<dim3(32, 16), blk, 0, stream>>>(hs16, Wsc, (void*)Qb, nullptr,
                                                        2048, 4096, 4096);
  // Wk|Wv -> contiguous bf16 (2048x4096), fused KV projection
  cvt_bf16<<<2048, blk, 0, stream>>>((const float4*)Wk, (uint4*)Wsc, 524288);
  cvt_bf16<<<2048, blk, 0, stream>>>((const float4*)Wv, (uint4*)(Wsc + 1024 * 4096), 524288);
  gemm16<true, true><<<dim3(16, 16), blk, 0, stream>>>(hs16, Wsc, (void*)Kb, (void*)Vb,
                                                       2048, 2048, 4096);
  // RoPE in-place on Q (with 1/sqrt(128) folded in) and K
  rope_kernel<<<16384, blk, 0, stream>>>((u32*)Qb, NH, 2048 * NH * 64, 0.08838834764831845f);
  rope_kernel<<<4096, blk, 0, stream>>>((u32*)Kb, NKV, 2048 * NKV * 64, 1.0f);
  // Wo -> bf16 while attention runs next
  cvt_bf16<<<8192, blk, 0, stream>>>((const float4*)Wo, (uint4*)Wsc, 2097152);
  // causal GQA MFMA flash attention -> Ob bf16
  attn_kernel<<<dim3(S_LEN / 64, NH, 2), blk, 0, stream>>>((const u32*)Qb, (const u32*)Kb,
                                                           (const u32*)Vb, (u32*)Ob);
  // output projection: bf16 x bf16 -> fp32 overwrites d_out
  gemm16<false, false><<<dim3(32, 16), blk, 0, stream>>>(Ob, Wsc, d_out, nullptr,
                                                         2048, 4096, 4096);
}

// Round 4
// 620.974 us; speedup vs baseline: 2.6835x; 1.0187x over previous
//
#include <hip/hip_runtime.h>

typedef unsigned int u32;
typedef unsigned short u16;

#define S_LEN 1024
#define NH 32
#define NKV 8
#define DW 64      // dwords per head row (128 bf16 = 64 u32)
#define NEG_BIG (-1e30f)

typedef __bf16 bf16x8 __attribute__((ext_vector_type(8)));
typedef float f32x4 __attribute__((ext_vector_type(4)));

__device__ __forceinline__ u16 f2bf(float f) {
  u32 u = __builtin_bit_cast(u32, f);
  u += 0x7fffu + ((u >> 16) & 1u);   // RNE
  return (u16)(u >> 16);
}
__device__ __forceinline__ float bflo(u32 u) { return __builtin_bit_cast(float, u << 16); }
__device__ __forceinline__ float bfhi(u32 u) { return __builtin_bit_cast(float, u & 0xffff0000u); }

// global -> LDS direct DMA, 16B per lane. LDS dest is wave-uniform base;
// HW writes lane l at base + l*16 (m97-verified pattern).
__device__ __forceinline__ void gl_lds16(const u16* g, u32* l) {
  __builtin_amdgcn_global_load_lds(
      (__attribute__((address_space(1))) void*)const_cast<u16*>(g),
      (__attribute__((address_space(3))) void*)l, 16, 0, 0);
}

// ---------------------------------------------------------------------------
// fp32 -> bf16 streaming conversion, 8 elems/thread (32B read, 16B write).
// ---------------------------------------------------------------------------
__launch_bounds__(256)
__global__ void cvt_bf16(const float4* __restrict__ in, uint4* __restrict__ out, int n8) {
  int i = blockIdx.x * 256 + threadIdx.x;
  if (i >= n8) return;
  float4 a = in[2 * i], b = in[2 * i + 1];
  uint4 o;
  o.x = (u32)f2bf(a.x) | ((u32)f2bf(a.y) << 16);
  o.y = (u32)f2bf(a.z) | ((u32)f2bf(a.w) << 16);
  o.z = (u32)f2bf(b.x) | ((u32)f2bf(b.y) << 16);
  o.w = (u32)f2bf(b.z) | ((u32)f2bf(b.w) << 16);
  out[i] = o;
}

// ---------------------------------------------------------------------------
// C = A @ B^T, all-bf16 inputs.  A: (M,K) bf16.  B: (N,K) bf16 row-major.
// C: bf16 (BF16OUT) or fp32.  128x128 tile, 4 waves, 4x4 MFMA 16x16x32 tiles.
// Staging via global_load_lds (16B/lane, lane-linear LDS == As[row][32bf16]).
// Fragment layouts (m92/m97-verified). Unchanged from r3 (passing).
// ---------------------------------------------------------------------------
template <bool BF16OUT, bool SPLIT>
__launch_bounds__(256)
__global__ void gemm16(const u16* __restrict__ A, const u16* __restrict__ B,
                       void* __restrict__ Cv, void* __restrict__ Cv2,
                       int M, int N, int K) {
  __shared__ u32 As[128 * 16];   // 128 rows x 32 bf16 (8 KB)
  __shared__ u32 Bs[128 * 16];
  const int tid = threadIdx.x;
  const int lane = tid & 63, w = tid >> 6;
  const int wr = w >> 1, wc = w & 1;
  const int col = lane & 15, quad = lane >> 4;
  const int nwg = gridDim.x * gridDim.y;
  const int bid = blockIdx.y * gridDim.x + blockIdx.x;
  const int cpx = nwg >> 3;
  const int sw = (bid & 7) * cpx + (bid >> 3);
  const int m0 = (sw / gridDim.x) * 128, n0 = (sw % gridDim.x) * 128;

  const u16* ap0 = A + (size_t)(m0 + (tid >> 2)) * K + (tid & 3) * 8;
  const u16* ap1 = ap0 + (size_t)64 * K;
  const u16* bp0 = B + (size_t)(n0 + (tid >> 2)) * K + (tid & 3) * 8;
  const u16* bp1 = bp0 + (size_t)64 * K;
  u32* asd0 = &As[w * 256];
  u32* asd1 = &As[1024 + w * 256];
  u32* bsd0 = &Bs[w * 256];
  u32* bsd1 = &Bs[1024 + w * 256];

  f32x4 acc[4][4] = {};

  for (int k0 = 0; k0 < K; k0 += 32) {
    gl_lds16(ap0 + k0, asd0);
    gl_lds16(ap1 + k0, asd1);
    gl_lds16(bp0 + k0, bsd0);
    gl_lds16(bp1 + k0, bsd1);
    __syncthreads();

    bf16x8 af[4], bfr[4];
#pragma unroll
    for (int i = 0; i < 4; ++i) {
      int m = wr * 64 + i * 16 + col;
      af[i] = *reinterpret_cast<const bf16x8*>(&As[m * 16 + quad * 4]);
      int n = wc * 64 + i * 16 + col;
      bfr[i] = *reinterpret_cast<const bf16x8*>(&Bs[n * 16 + quad * 4]);
    }
#pragma unroll
    for (int i = 0; i < 4; ++i)
#pragma unroll
      for (int j = 0; j < 4; ++j)
        acc[i][j] = __builtin_amdgcn_mfma_f32_16x16x32_bf16(af[i], bfr[j], acc[i][j], 0, 0, 0);
    __syncthreads();
  }

#pragma unroll
  for (int i = 0; i < 4; ++i)
#pragma unroll
    for (int j = 0; j < 4; ++j)
#pragma unroll
      for (int r = 0; r < 4; ++r) {
        int row = m0 + wr * 64 + i * 16 + quad * 4 + r;
        int cc  = n0 + wc * 64 + j * 16 + col;
        float v = acc[i][j][r];
        if constexpr (SPLIT) {
          u16* dst = (cc >> 10) ? (u16*)Cv2 : (u16*)Cv;
          dst[(size_t)row * 1024 + (cc & 1023)] = f2bf(v);
        } else if constexpr (BF16OUT) {
          ((u16*)Cv)[(size_t)row * N + cc] = f2bf(v);
        } else {
          ((float*)Cv)[(size_t)row * N + cc] = v;
        }
      }
}

// ---------------------------------------------------------------------------
// In-place RoPE on bf16. out_scale folds 1/sqrt(HEAD_DIM) into Q for free.
// ---------------------------------------------------------------------------
__launch_bounds__(256)
__global__ void rope_kernel(u32* __restrict__ buf, int heads, int npairs, float out_scale) {
  int p = blockIdx.x * 256 + threadIdx.x;
  if (p >= npairs) return;
  int d2 = p & 63;
  int s = (p / (64 * heads)) % S_LEN;
  float ang = (float)s * expf((float)d2 * -0.14391156831212787f);
  float sn, cs;
  sincosf(ang, &sn, &cs);
  u32 u = buf[p];
  float x0 = bflo(u), x1 = bfhi(u);
  float y0 = (x0 * cs - x1 * sn) * out_scale;
  float y1 = (x0 * sn + x1 * cs) * out_scale;
  buf[p] = (u32)f2bf(y0) | ((u32)f2bf(y1) << 16);
}

// ---------------------------------------------------------------------------
// MFMA flash attention (causal GQA, online softmax).
// r4 changes (imbalance theory: r3 counters Occupancy 12.5%, all pipes idle):
//  * complementary-pair balancing: 1-D grid of 512 blocks; block processes
//    q-tile (15-p) then q-tile p => every block = exactly 17 KV-tile units
//    (was 1..16, 16x spread with idle drain tail).
//  * XCD-locality id layout: id = kh + 8*j, so all 64 blocks sharing one
//    kh land on one XCD (id%8 round-robin heuristic) -> K/V panel (1 MB)
//    stays in that XCD's L2.
//  * cross-half prefetch: last tile of half 0 prefetches tile 0 of half 1.
//  * T5 s_setprio(1) around MFMA clusters (m191: +4-7% attn).
// Per-tile structure unchanged from r3 (verified passing).
// ---------------------------------------------------------------------------
__launch_bounds__(256)
__global__ void attn_kernel(const u32* __restrict__ Qb, const u32* __restrict__ Kb,
                            const u32* __restrict__ Vb, u32* __restrict__ Ob) {
  __shared__ u32 Ks[64 * 64];      // 16 KB
  __shared__ u32 Vt[128 * 32];     // 16 KB
  __shared__ u16 Ps[4][16 * 64];   // 8 KB
  const int tid = threadIdx.x, lane = tid & 63, w = tid >> 6;
  const int col = lane & 15, quad = lane >> 4;
  // id = kh + 8*(b + 2*(hin + 4*pair)): same kh => same id%8 => same XCD
  const int id = blockIdx.x;
  const int kh = id & 7;
  const int j2 = id >> 3;
  const int b = j2 & 1, hin = (j2 >> 1) & 3, pair = j2 >> 3;   // pair 0..7
  const int h = kh * 4 + hin;

  uint4 kpf[4], vpa[2], vpb[2];
  auto prefetch = [&](int t0) {
#pragma unroll
    for (int i = 0; i < 4; ++i) {
      int f = i * 256 + tid;
      int row = f >> 4, c4 = f & 15;
      kpf[i] = *((const uint4*)(Kb + ((size_t)((b * S_LEN + t0 + row) * NKV + kh)) * DW) + c4);
    }
#pragma unroll
    for (int i = 0; i < 2; ++i) {
      int f = i * 256 + tid;
      int kp = f & 31, c8 = f >> 5;
      size_t base0 = ((size_t)((b * S_LEN + t0 + 2 * kp) * NKV + kh)) * DW;
      vpa[i] = *((const uint4*)(Vb + base0) + c8);
      vpb[i] = *((const uint4*)(Vb + base0 + (size_t)NKV * DW) + c8);
    }
  };

  prefetch(0);   // first tile of half 0

  for (int half = 0; half < 2; ++half) {
    const int jt = half ? pair : (15 - pair);   // heavy q-tile first
    const int q0 = jt * 64 + w * 16;

    // Q fragments: lane holds Q[q0+col][d = dc*32 + quad*8 + j]
    bf16x8 qf[4];
    {
      const u32* qrow = Qb + ((size_t)((b * S_LEN + q0 + col) * NH + h)) * DW;
#pragma unroll
      for (int dc = 0; dc < 4; ++dc)
        qf[dc] = *reinterpret_cast<const bf16x8*>(qrow + dc * 16 + quad * 4);
    }

    float m_r[4], l_r[4];
    f32x4 oacc[8];
#pragma unroll
    for (int r = 0; r < 4; ++r) { m_r[r] = NEG_BIG; l_r[r] = 0.f; }
#pragma unroll
    for (int dt = 0; dt < 8; ++dt) oacc[dt] = (f32x4){0.f, 0.f, 0.f, 0.f};

    for (int tt = 0; tt <= jt; ++tt) {
      const int t0 = tt * 64;
      __syncthreads();   // readers of prev tile done; drains vmcnt of prefetch
      // ---- stage K from prefetch regs ----
#pragma unroll
      for (int i = 0; i < 4; ++i) {
        int f = i * 256 + tid;
        int row = f >> 4, c4 = f & 15;
        *(uint4*)&Ks[(row * 64 + c4 * 4) ^ ((row & 7) << 2)] = kpf[i];
      }
      // ---- stage V transposed from prefetch regs ----
#pragma unroll
      for (int i = 0; i < 2; ++i) {
        int f = i * 256 + tid;
        int kp = f & 31, c8 = f >> 5;
        u32 a[4] = {vpa[i].x, vpa[i].y, vpa[i].z, vpa[i].w};
        u32 bbv[4] = {vpb[i].x, vpb[i].y, vpb[i].z, vpb[i].w};
#pragma unroll
        for (int t = 0; t < 4; ++t) {
          int d0 = c8 * 8 + 2 * t, d1 = d0 + 1;
          u32 lo = (a[t] & 0xffffu) | (bbv[t] << 16);
          u32 hi = (a[t] >> 16) | (bbv[t] & 0xffff0000u);
          Vt[(d0 * 32 + kp) ^ ((d0 & 7) << 2)] = lo;
          Vt[(d1 * 32 + kp) ^ ((d1 & 7) << 2)] = hi;
        }
      }
      __syncthreads();   // LDS tile published

      // ---- issue next-tile loads (crosses the half boundary too) ----
      if (tt < jt) prefetch(t0 + 64);
      else if (half == 0) prefetch(0);

      // ---- QK^T ----
      f32x4 sacc[4];
#pragma unroll
      for (int kt = 0; kt < 4; ++kt) sacc[kt] = (f32x4){0.f, 0.f, 0.f, 0.f};
      __builtin_amdgcn_s_setprio(1);
#pragma unroll
      for (int dc = 0; dc < 4; ++dc)
#pragma unroll
        for (int kt = 0; kt < 4; ++kt) {
          int key = kt * 16 + col;
          bf16x8 kf = *reinterpret_cast<const bf16x8*>(
              &Ks[(key * 64 + dc * 16 + quad * 4) ^ ((key & 7) << 2)]);
          sacc[kt] = __builtin_amdgcn_mfma_f32_16x16x32_bf16(qf[dc], kf, sacc[kt], 0, 0, 0);
        }
      __builtin_amdgcn_s_setprio(0);

      // ---- causal mask (diagonal tile only) ----
      if (tt == jt) {
#pragma unroll
        for (int kt = 0; kt < 4; ++kt)
#pragma unroll
          for (int r = 0; r < 4; ++r) {
            int tg = t0 + kt * 16 + col;
            int qg = q0 + quad * 4 + r;
            if (tg > qg) sacc[kt][r] = NEG_BIG;
          }
      }

      // ---- online softmax (4 rows per lane, 16-lane-group reduce) ----
      float mt[4];
#pragma unroll
      for (int r = 0; r < 4; ++r)
        mt[r] = fmaxf(fmaxf(sacc[0][r], sacc[1][r]), fmaxf(sacc[2][r], sacc[3][r]));
#pragma unroll
      for (int off = 1; off < 16; off <<= 1)
#pragma unroll
        for (int r = 0; r < 4; ++r) mt[r] = fmaxf(mt[r], __shfl_xor(mt[r], off));
      float alpha[4], ps[4];
#pragma unroll
      for (int r = 0; r < 4; ++r) {
        float mn = fmaxf(m_r[r], mt[r]);
        alpha[r] = __expf(m_r[r] - mn);
        m_r[r] = mn;
        ps[r] = 0.f;
      }
#pragma unroll
      for (int kt = 0; kt < 4; ++kt)
#pragma unroll
        for (int r = 0; r < 4; ++r) {
          float p = __expf(sacc[kt][r] - m_r[r]);
          u16 pb = f2bf(p);
          int rw = quad * 4 + r;
          Ps[w][(rw * 64 + kt * 16 + col) ^ ((rw & 7) << 3)] = pb;
          ps[r] += bflo((u32)pb);
        }
#pragma unroll
      for (int off = 1; off < 16; off <<= 1)
#pragma unroll
        for (int r = 0; r < 4; ++r) ps[r] += __shfl_xor(ps[r], off);
#pragma unroll
      for (int r = 0; r < 4; ++r) l_r[r] = l_r[r] * alpha[r] + ps[r];
#pragma unroll
      for (int dt = 0; dt < 8; ++dt)
#pragma unroll
        for (int r = 0; r < 4; ++r) oacc[dt][r] *= alpha[r];

      // ---- PV ----
      bf16x8 pa[2];
#pragma unroll
      for (int ks = 0; ks < 2; ++ks)
        pa[ks] = *reinterpret_cast<const bf16x8*>(
            &Ps[w][(col * 64 + ks * 32 + quad * 8) ^ ((col & 7) << 3)]);
      __builtin_amdgcn_s_setprio(1);
#pragma unroll
      for (int dt = 0; dt < 8; ++dt) {
        int d = dt * 16 + col;
#pragma unroll
        for (int ks = 0; ks < 2; ++ks) {
          bf16x8 vf = *reinterpret_cast<const bf16x8*>(
              &Vt[(d * 32 + ks * 16 + quad * 4) ^ ((d & 7) << 2)]);
          oacc[dt] = __builtin_amdgcn_mfma_f32_16x16x32_bf16(pa[ks], vf, oacc[dt], 0, 0, 0);
        }
      }
      __builtin_amdgcn_s_setprio(0);
    }

    // ---- epilogue for this q-tile ----
    float invl[4];
#pragma unroll
    for (int r = 0; r < 4; ++r) invl[r] = 1.0f / l_r[r];
    u16* O16 = (u16*)Ob;
#pragma unroll
    for (int dt = 0; dt < 8; ++dt)
#pragma unroll
      for (int r = 0; r < 4; ++r) {
        int qg = q0 + quad * 4 + r;
        int d = dt * 16 + col;
        O16[((size_t)((b * S_LEN + qg) * NH + h)) * 128 + d] = f2bf(oacc[dt][r] * invl[r]);
      }
  }
}

// ---------------------------------------------------------------------------
// fp32 in / fp32 out. Internals bf16 via one-shot conversion kernels.
// d_out: [0,16M) Qb bf16 | [16M,32M) hs16 bf16 (dead before final GEMM write).
// ws:    [0,4M) Kb | [4M,8M) Vb | [8M,24M) Ob | [24M,56M) W-scratch
//        (Wq16 -> Wkv16 -> Wo16, serialized reuse; stream-ordered).
// ---------------------------------------------------------------------------
extern "C" void kernel_launch(void* const* d_in, const int* in_sizes, int n_in,
                              void* d_out, int out_size, void* d_ws, size_t ws_size,
                              hipStream_t stream) {
  const float* hs = (const float*)d_in[0];
  const float* Wq = (const float*)d_in[1];
  const float* Wk = (const float*)d_in[2];
  const float* Wv = (const float*)d_in[3];
  const float* Wo = (const float*)d_in[4];

  u16* Qb   = (u16*)d_out;
  u16* hs16 = (u16*)((char*)d_out + (16u << 20));
  char* ws = (char*)d_ws;
  u16* Kb  = (u16*)ws;
  u16* Vb  = (u16*)(ws + (4u << 20));
  u16* Ob  = (u16*)(ws + (8u << 20));
  u16* Wsc = (u16*)(ws + (24u << 20));   // 32 MB serialized scratch

  dim3 blk(256);
  cvt_bf16<<<4096, blk, 0, stream>>>((const float4*)hs, (uint4*)hs16, 1048576);
  cvt_bf16<<<8192, blk, 0, stream>>>((const float4*)Wq, (uint4*)Wsc, 2097152);
  gemm16<true, false><<<dim3(32, 16), blk, 0, stream>>>(hs16, Wsc, (void*)Qb, nullptr,
                                                        2048, 4096, 4096);
  cvt_bf16<<<2048, blk, 0, stream>>>((const float4*)Wk, (uint4*)Wsc, 524288);
  cvt_bf16<<<2048, blk, 0, stream>>>((const float4*)Wv, (uint4*)(Wsc + 1024 * 4096), 524288);
  gemm16<true, true><<<dim3(16, 16), blk, 0, stream>>>(hs16, Wsc, (void*)Kb, (void*)Vb,
                                                       2048, 2048, 4096);
  rope_kernel<<<16384, blk, 0, stream>>>((u32*)Qb, NH, 2048 * NH * 64, 0.08838834764831845f);
  rope_kernel<<<4096, blk, 0, stream>>>((u32*)Kb, NKV, 2048 * NKV * 64, 1.0f);
  cvt_bf16<<<8192, blk, 0, stream>>>((const float4*)Wo, (uint4*)Wsc, 2097152);
  attn_kernel<<<dim3(512), blk, 0, stream>>>((const u32*)Qb, (const u32*)Kb,
                                             (const u32*)Vb, (u32*)Ob);
  gemm16<false, false><<<dim3(32, 16), blk, 0, stream>>>(Ob, Wsc, d_out, nullptr,
                                                         2048, 4096, 4096);
}

// Round 5
// 547.072 us; speedup vs baseline: 3.0460x; 1.1351x over previous
//
#include <hip/hip_runtime.h>

typedef unsigned int u32;
typedef unsigned short u16;

#define S_LEN 1024
#define NH 32
#define NKV 8
#define DW 64      // dwords per head row (128 bf16 = 64 u32)
#define NEG_BIG (-1e30f)

typedef __bf16 bf16x8 __attribute__((ext_vector_type(8)));
typedef float f32x4 __attribute__((ext_vector_type(4)));

__device__ __forceinline__ u16 f2bf(float f) {
  u32 u = __builtin_bit_cast(u32, f);
  u += 0x7fffu + ((u >> 16) & 1u);   // RNE
  return (u16)(u >> 16);
}
__device__ __forceinline__ float bflo(u32 u) { return __builtin_bit_cast(float, u << 16); }
__device__ __forceinline__ float bfhi(u32 u) { return __builtin_bit_cast(float, u & 0xffff0000u); }

// global -> LDS direct DMA, 16B per lane. LDS dest is wave-uniform base;
// HW writes lane l at base + l*16 (m97-verified pattern).
__device__ __forceinline__ void gl_lds16(const u16* g, u32* l) {
  __builtin_amdgcn_global_load_lds(
      (__attribute__((address_space(1))) void*)const_cast<u16*>(g),
      (__attribute__((address_space(3))) void*)l, 16, 0, 0);
}

// ---------------------------------------------------------------------------
// Fused fp32 -> bf16 conversion for hs, Wq, Wk, Wv (one launch, 16384 blocks).
// Wq/Wk/Wv land concatenated in Wqkv16 (6144 x 4096 bf16): rows [0,4096) Wq,
// [4096,5120) Wk, [5120,6144) Wv. 8 elems/thread (32B read, 16B write).
// ---------------------------------------------------------------------------
__launch_bounds__(256)
__global__ void cvt_all(const float4* __restrict__ hs, const float4* __restrict__ wq,
                        const float4* __restrict__ wk, const float4* __restrict__ wv,
                        uint4* __restrict__ hs16, uint4* __restrict__ wqkv) {
  const int b = blockIdx.x;
  const float4* src;
  uint4* dst;
  int i;
  if (b < 4096)       { i = b * 256 + threadIdx.x;           src = hs; dst = hs16; }
  else if (b < 12288) { i = (b - 4096) * 256 + threadIdx.x;  src = wq; dst = wqkv; }
  else if (b < 14336) { i = (b - 12288) * 256 + threadIdx.x; src = wk; dst = wqkv + 2097152; }
  else                { i = (b - 14336) * 256 + threadIdx.x; src = wv; dst = wqkv + 2621440; }
  float4 a = src[2 * i], c = src[2 * i + 1];
  uint4 o;
  o.x = (u32)f2bf(a.x) | ((u32)f2bf(a.y) << 16);
  o.y = (u32)f2bf(a.z) | ((u32)f2bf(a.w) << 16);
  o.z = (u32)f2bf(c.x) | ((u32)f2bf(c.y) << 16);
  o.w = (u32)f2bf(c.z) | ((u32)f2bf(c.w) << 16);
  dst[i] = o;
}

// plain fp32 -> bf16 (used for Wo after the QKV GEMM frees its ws region)
__launch_bounds__(256)
__global__ void cvt_bf16(const float4* __restrict__ in, uint4* __restrict__ out, int n8) {
  int i = blockIdx.x * 256 + threadIdx.x;
  if (i >= n8) return;
  float4 a = in[2 * i], b = in[2 * i + 1];
  uint4 o;
  o.x = (u32)f2bf(a.x) | ((u32)f2bf(a.y) << 16);
  o.y = (u32)f2bf(a.z) | ((u32)f2bf(a.w) << 16);
  o.z = (u32)f2bf(b.x) | ((u32)f2bf(b.y) << 16);
  o.w = (u32)f2bf(b.z) | ((u32)f2bf(b.w) << 16);
  out[i] = o;
}

// ---------------------------------------------------------------------------
// C = A @ B^T, all-bf16 inputs.  A: (M,K) bf16.  B: (N,K) bf16 row-major.
// 128x128 tile, 4 waves, 4x4 MFMA 16x16x32 tiles; global_load_lds staging.
// Fragment layouts (m92/m97-verified):
//   A-frag: A[m=lane&15][k=quad*8+j];  B-frag from B^T: B[n=lane&15][k=quad*8+j]
//   C/D:    row = quad*4+reg, col = lane&15
// r5: XCD chunk remapped from 2-full-rows to an 8m x (cpx/8)n RECTANGLE
// (n-fast inner) — r4 counters showed FETCH 139 MB vs 48 MB input (B panel
// swept per row). Valid/bijective for gy=16, cpx%8==0 (all our launches).
// MODE: 0 = fp32 out single; 2 = QKV triple-route (N=6144: Q|K|V epilogue).
// ---------------------------------------------------------------------------
template <int MODE>
__launch_bounds__(256)
__global__ void gemm16(const u16* __restrict__ A, const u16* __restrict__ B,
                       void* __restrict__ C0, void* __restrict__ C1,
                       void* __restrict__ C2, int M, int N, int K) {
  __shared__ u32 As[128 * 16];   // 128 rows x 32 bf16 (8 KB)
  __shared__ u32 Bs[128 * 16];
  const int tid = threadIdx.x;
  const int lane = tid & 63, w = tid >> 6;
  const int wr = w >> 1, wc = w & 1;
  const int col = lane & 15, quad = lane >> 4;
  // XCD-rectangle swizzle: chunk x (= bid&7, the XCD) owns an 8 x chn tile
  // rectangle; within-chunk order is n-fast (A-panel stays L2-hot).
  const int nwg = gridDim.x * gridDim.y;       // 512 or 768
  const int bid = blockIdx.y * gridDim.x + blockIdx.x;
  const int cpx = nwg >> 3;                    // 64 or 96
  const int chn = cpx >> 3;                    // 8 or 12 (chunk = 8m x chn n)
  const int xcd = bid & 7, q = bid >> 3;
  const int cm = xcd >> 2, cn = xcd & 3;       // chunk grid 2 x 4
  const int im = q / chn, in_ = q % chn;
  const int m0 = (cm * 8 + im) * 128;
  const int n0 = (cn * chn + in_) * 128;

  const u16* ap0 = A + (size_t)(m0 + (tid >> 2)) * K + (tid & 3) * 8;
  const u16* ap1 = ap0 + (size_t)64 * K;
  const u16* bp0 = B + (size_t)(n0 + (tid >> 2)) * K + (tid & 3) * 8;
  const u16* bp1 = bp0 + (size_t)64 * K;
  u32* asd0 = &As[w * 256];
  u32* asd1 = &As[1024 + w * 256];
  u32* bsd0 = &Bs[w * 256];
  u32* bsd1 = &Bs[1024 + w * 256];

  f32x4 acc[4][4] = {};

  for (int k0 = 0; k0 < K; k0 += 32) {
    gl_lds16(ap0 + k0, asd0);
    gl_lds16(ap1 + k0, asd1);
    gl_lds16(bp0 + k0, bsd0);
    gl_lds16(bp1 + k0, bsd1);
    __syncthreads();

    bf16x8 af[4], bfr[4];
#pragma unroll
    for (int i = 0; i < 4; ++i) {
      int m = wr * 64 + i * 16 + col;
      af[i] = *reinterpret_cast<const bf16x8*>(&As[m * 16 + quad * 4]);
      int n = wc * 64 + i * 16 + col;
      bfr[i] = *reinterpret_cast<const bf16x8*>(&Bs[n * 16 + quad * 4]);
    }
#pragma unroll
    for (int i = 0; i < 4; ++i)
#pragma unroll
      for (int j = 0; j < 4; ++j)
        acc[i][j] = __builtin_amdgcn_mfma_f32_16x16x32_bf16(af[i], bfr[j], acc[i][j], 0, 0, 0);
    __syncthreads();
  }

#pragma unroll
  for (int i = 0; i < 4; ++i)
#pragma unroll
    for (int j = 0; j < 4; ++j)
#pragma unroll
      for (int r = 0; r < 4; ++r) {
        int row = m0 + wr * 64 + i * 16 + quad * 4 + r;   // C/D: row = quad*4+reg
        int cc  = n0 + wc * 64 + j * 16 + col;            //      col = lane&15
        float v = acc[i][j][r];
        if constexpr (MODE == 2) {
          // N=6144 QKV: n<4096 -> Q (stride 4096); 4096..5119 -> K; else V.
          if (cc < 4096)      ((u16*)C0)[(size_t)row * 4096 + cc] = f2bf(v);
          else if (cc < 5120) ((u16*)C1)[(size_t)row * 1024 + (cc - 4096)] = f2bf(v);
          else                ((u16*)C2)[(size_t)row * 1024 + (cc - 5120)] = f2bf(v);
        } else {
          ((float*)C0)[(size_t)row * N + cc] = v;
        }
      }
}

// ---------------------------------------------------------------------------
// Fused RoPE: blocks [0,16384) handle Q (scale = 1/sqrt(128) folded in),
// [16384,20480) handle K. Exact grids, no bounds checks.
// ---------------------------------------------------------------------------
__launch_bounds__(256)
__global__ void rope_all(u32* __restrict__ Qb, u32* __restrict__ Kb) {
  int pg = blockIdx.x * 256 + threadIdx.x;
  u32* buf;
  int p, heads;
  float scale;
  if (pg < 4194304) { buf = Qb; p = pg; heads = NH; scale = 0.08838834764831845f; }
  else              { buf = Kb; p = pg - 4194304; heads = NKV; scale = 1.0f; }
  int d2 = p & 63;
  int s = (p / (64 * heads)) % S_LEN;
  float ang = (float)s * expf((float)d2 * -0.14391156831212787f);
  float sn, cs;
  sincosf(ang, &sn, &cs);   // accurate range reduction (ang up to ~1023 rad)
  u32 u = buf[p];
  float x0 = bflo(u), x1 = bfhi(u);
  float y0 = (x0 * cs - x1 * sn) * scale;
  float y1 = (x0 * sn + x1 * cs) * scale;
  buf[p] = (u32)f2bf(y0) | ((u32)f2bf(y1) << 16);
}

// ---------------------------------------------------------------------------
// MFMA flash attention (causal GQA, online softmax). Unchanged from r4
// (complementary-pair balance, XCD-locality ids, reg-prefetch, setprio).
// ---------------------------------------------------------------------------
__launch_bounds__(256)
__global__ void attn_kernel(const u32* __restrict__ Qb, const u32* __restrict__ Kb,
                            const u32* __restrict__ Vb, u32* __restrict__ Ob) {
  __shared__ u32 Ks[64 * 64];      // 16 KB
  __shared__ u32 Vt[128 * 32];     // 16 KB
  __shared__ u16 Ps[4][16 * 64];   // 8 KB
  const int tid = threadIdx.x, lane = tid & 63, w = tid >> 6;
  const int col = lane & 15, quad = lane >> 4;
  const int id = blockIdx.x;
  const int kh = id & 7;
  const int j2 = id >> 3;
  const int b = j2 & 1, hin = (j2 >> 1) & 3, pair = j2 >> 3;   // pair 0..7
  const int h = kh * 4 + hin;

  uint4 kpf[4], vpa[2], vpb[2];
  auto prefetch = [&](int t0) {
#pragma unroll
    for (int i = 0; i < 4; ++i) {
      int f = i * 256 + tid;
      int row = f >> 4, c4 = f & 15;
      kpf[i] = *((const uint4*)(Kb + ((size_t)((b * S_LEN + t0 + row) * NKV + kh)) * DW) + c4);
    }
#pragma unroll
    for (int i = 0; i < 2; ++i) {
      int f = i * 256 + tid;
      int kp = f & 31, c8 = f >> 5;
      size_t base0 = ((size_t)((b * S_LEN + t0 + 2 * kp) * NKV + kh)) * DW;
      vpa[i] = *((const uint4*)(Vb + base0) + c8);
      vpb[i] = *((const uint4*)(Vb + base0 + (size_t)NKV * DW) + c8);
    }
  };

  prefetch(0);   // first tile of half 0

  for (int half = 0; half < 2; ++half) {
    const int jt = half ? pair : (15 - pair);   // heavy q-tile first
    const int q0 = jt * 64 + w * 16;

    bf16x8 qf[4];
    {
      const u32* qrow = Qb + ((size_t)((b * S_LEN + q0 + col) * NH + h)) * DW;
#pragma unroll
      for (int dc = 0; dc < 4; ++dc)
        qf[dc] = *reinterpret_cast<const bf16x8*>(qrow + dc * 16 + quad * 4);
    }

    float m_r[4], l_r[4];
    f32x4 oacc[8];
#pragma unroll
    for (int r = 0; r < 4; ++r) { m_r[r] = NEG_BIG; l_r[r] = 0.f; }
#pragma unroll
    for (int dt = 0; dt < 8; ++dt) oacc[dt] = (f32x4){0.f, 0.f, 0.f, 0.f};

    for (int tt = 0; tt <= jt; ++tt) {
      const int t0 = tt * 64;
      __syncthreads();   // readers of prev tile done; drains vmcnt of prefetch
#pragma unroll
      for (int i = 0; i < 4; ++i) {
        int f = i * 256 + tid;
        int row = f >> 4, c4 = f & 15;
        *(uint4*)&Ks[(row * 64 + c4 * 4) ^ ((row & 7) << 2)] = kpf[i];
      }
#pragma unroll
      for (int i = 0; i < 2; ++i) {
        int f = i * 256 + tid;
        int kp = f & 31, c8 = f >> 5;
        u32 a[4] = {vpa[i].x, vpa[i].y, vpa[i].z, vpa[i].w};
        u32 bbv[4] = {vpb[i].x, vpb[i].y, vpb[i].z, vpb[i].w};
#pragma unroll
        for (int t = 0; t < 4; ++t) {
          int d0 = c8 * 8 + 2 * t, d1 = d0 + 1;
          u32 lo = (a[t] & 0xffffu) | (bbv[t] << 16);
          u32 hi = (a[t] >> 16) | (bbv[t] & 0xffff0000u);
          Vt[(d0 * 32 + kp) ^ ((d0 & 7) << 2)] = lo;
          Vt[(d1 * 32 + kp) ^ ((d1 & 7) << 2)] = hi;
        }
      }
      __syncthreads();   // LDS tile published

      if (tt < jt) prefetch(t0 + 64);
      else if (half == 0) prefetch(0);

      f32x4 sacc[4];
#pragma unroll
      for (int kt = 0; kt < 4; ++kt) sacc[kt] = (f32x4){0.f, 0.f, 0.f, 0.f};
      __builtin_amdgcn_s_setprio(1);
#pragma unroll
      for (int dc = 0; dc < 4; ++dc)
#pragma unroll
        for (int kt = 0; kt < 4; ++kt) {
          int key = kt * 16 + col;
          bf16x8 kf = *reinterpret_cast<const bf16x8*>(
              &Ks[(key * 64 + dc * 16 + quad * 4) ^ ((key & 7) << 2)]);
          sacc[kt] = __builtin_amdgcn_mfma_f32_16x16x32_bf16(qf[dc], kf, sacc[kt], 0, 0, 0);
        }
      __builtin_amdgcn_s_setprio(0);

      if (tt == jt) {
#pragma unroll
        for (int kt = 0; kt < 4; ++kt)
#pragma unroll
          for (int r = 0; r < 4; ++r) {
            int tg = t0 + kt * 16 + col;
            int qg = q0 + quad * 4 + r;
            if (tg > qg) sacc[kt][r] = NEG_BIG;
          }
      }

      float mt[4];
#pragma unroll
      for (int r = 0; r < 4; ++r)
        mt[r] = fmaxf(fmaxf(sacc[0][r], sacc[1][r]), fmaxf(sacc[2][r], sacc[3][r]));
#pragma unroll
      for (int off = 1; off < 16; off <<= 1)
#pragma unroll
        for (int r = 0; r < 4; ++r) mt[r] = fmaxf(mt[r], __shfl_xor(mt[r], off));
      float alpha[4], ps[4];
#pragma unroll
      for (int r = 0; r < 4; ++r) {
        float mn = fmaxf(m_r[r], mt[r]);
        alpha[r] = __expf(m_r[r] - mn);
        m_r[r] = mn;
        ps[r] = 0.f;
      }
#pragma unroll
      for (int kt = 0; kt < 4; ++kt)
#pragma unroll
        for (int r = 0; r < 4; ++r) {
          float p = __expf(sacc[kt][r] - m_r[r]);
          u16 pb = f2bf(p);
          int rw = quad * 4 + r;
          Ps[w][(rw * 64 + kt * 16 + col) ^ ((rw & 7) << 3)] = pb;
          ps[r] += bflo((u32)pb);
        }
#pragma unroll
      for (int off = 1; off < 16; off <<= 1)
#pragma unroll
        for (int r = 0; r < 4; ++r) ps[r] += __shfl_xor(ps[r], off);
#pragma unroll
      for (int r = 0; r < 4; ++r) l_r[r] = l_r[r] * alpha[r] + ps[r];
#pragma unroll
      for (int dt = 0; dt < 8; ++dt)
#pragma unroll
        for (int r = 0; r < 4; ++r) oacc[dt][r] *= alpha[r];

      bf16x8 pa[2];
#pragma unroll
      for (int ks = 0; ks < 2; ++ks)
        pa[ks] = *reinterpret_cast<const bf16x8*>(
            &Ps[w][(col * 64 + ks * 32 + quad * 8) ^ ((col & 7) << 3)]);
      __builtin_amdgcn_s_setprio(1);
#pragma unroll
      for (int dt = 0; dt < 8; ++dt) {
        int d = dt * 16 + col;
#pragma unroll
        for (int ks = 0; ks < 2; ++ks) {
          bf16x8 vf = *reinterpret_cast<const bf16x8*>(
              &Vt[(d * 32 + ks * 16 + quad * 4) ^ ((d & 7) << 2)]);
          oacc[dt] = __builtin_amdgcn_mfma_f32_16x16x32_bf16(pa[ks], vf, oacc[dt], 0, 0, 0);
        }
      }
      __builtin_amdgcn_s_setprio(0);
    }

    float invl[4];
#pragma unroll
    for (int r = 0; r < 4; ++r) invl[r] = 1.0f / l_r[r];
    u16* O16 = (u16*)Ob;
#pragma unroll
    for (int dt = 0; dt < 8; ++dt)
#pragma unroll
      for (int r = 0; r < 4; ++r) {
        int qg = q0 + quad * 4 + r;
        int d = dt * 16 + col;
        O16[((size_t)((b * S_LEN + qg) * NH + h)) * 128 + d] = f2bf(oacc[dt][r] * invl[r]);
      }
  }
}

// ---------------------------------------------------------------------------
// fp32 in / fp32 out. Internals bf16. 6 launches (was 11).
// d_out: [0,16M) Qb bf16 | [16M,32M) hs16 bf16 (dead before final GEMM write).
// ws (56 MB, serialized reuse):
//   [0,4M) Kb | [4,8M) Vb | [8,56M) Wqkv16 (48 MB, dead after QKV GEMM)
//   then: [8,24M) Ob (attn output) | [24,56M) Wo16 — both overwrite Wqkv16
//   strictly after gemm16<2> has consumed it (stream order).
// ---------------------------------------------------------------------------
extern "C" void kernel_launch(void* const* d_in, const int* in_sizes, int n_in,
                              void* d_out, int out_size, void* d_ws, size_t ws_size,
                              hipStream_t stream) {
  const float* hs = (const float*)d_in[0];
  const float* Wq = (const float*)d_in[1];
  const float* Wk = (const float*)d_in[2];
  const float* Wv = (const float*)d_in[3];
  const float* Wo = (const float*)d_in[4];

  u16* Qb   = (u16*)d_out;
  u16* hs16 = (u16*)((char*)d_out + (16u << 20));
  char* ws = (char*)d_ws;
  u16* Kb   = (u16*)ws;
  u16* Vb   = (u16*)(ws + (4u << 20));
  u16* Wqkv = (u16*)(ws + (8u << 20));   // 48 MB, dead after QKV GEMM
  u16* Ob   = (u16*)(ws + (8u << 20));   // 16 MB, written by attn (later)
  u16* Wo16 = (u16*)(ws + (24u << 20));  // 32 MB, written after QKV GEMM

  dim3 blk(256);
  // all fp32->bf16 conversions for stage 1 in one launch
  cvt_all<<<16384, blk, 0, stream>>>((const float4*)hs, (const float4*)Wq,
                                     (const float4*)Wk, (const float4*)Wv,
                                     (uint4*)hs16, (uint4*)Wqkv);
  // fused QKV projection: N = 6144 (Q|K|V), 768 blocks (3/CU)
  gemm16<2><<<dim3(48, 16), blk, 0, stream>>>(hs16, Wqkv, (void*)Qb, (void*)Kb,
                                              (void*)Vb, 2048, 6144, 4096);
  // fused RoPE on Q (scale folded) and K
  rope_all<<<20480, blk, 0, stream>>>((u32*)Qb, (u32*)Kb);
  // Wo -> bf16 into the now-free upper Wqkv region
  cvt_bf16<<<8192, blk, 0, stream>>>((const float4*)Wo, (uint4*)Wo16, 2097152);
  // causal GQA MFMA flash attention -> Ob (overwrites lower Wqkv region)
  attn_kernel<<<dim3(512), blk, 0, stream>>>((const u32*)Qb, (const u32*)Kb,
                                             (const u32*)Vb, (u32*)Ob);
  // output projection: bf16 x bf16 -> fp32 overwrites d_out
  gemm16<0><<<dim3(32, 16), blk, 0, stream>>>(Ob, Wo16, d_out, nullptr, nullptr,
                                              2048, 4096, 4096);
}